// Round 7
// baseline (53558.038 us; speedup 1.0000x reference)
//
#include <hip/hip_runtime.h>
#include <hip/hip_fp16.h>
#include <stdint.h>

#define IN_DIM 256
#define HID 512
#define OUT_DIM 128
#define BT 64
#define NSTEPS 40
#define TPB 512

typedef float f32x4 __attribute__((ext_vector_type(4)));
typedef __bf16 bf16x8 __attribute__((ext_vector_type(8)));

static __device__ __forceinline__ uint32_t f2bf(float f) {
  union { float f; uint32_t u; } v; v.f = f;
  uint32_t r = v.u + 0x7FFFu + ((v.u >> 16) & 1u);  // RNE
  return r >> 16;
}
static __device__ __forceinline__ float bflo(uint32_t u) {
  union { uint32_t u; float f; } v; v.u = u << 16; return v.f;
}
static __device__ __forceinline__ float bfhi(uint32_t u) {
  union { uint32_t u; float f; } v; v.u = u & 0xFFFF0000u; return v.f;
}
// fp16 pair pack/unpack (RNE! RTZ would systematically shrink h over 160 evals)
static __device__ __forceinline__ uint32_t pkh(float a, float b) {
  union { __half2 h; uint32_t u; } v;
  v.h.x = __float2half_rn(a);
  v.h.y = __float2half_rn(b);
  return v.u;
}
static __device__ __forceinline__ float h2lo(uint32_t u) {
  union { uint32_t u; __half2 h; } v; v.u = u;
  return __half2float(v.h.x);
}
static __device__ __forceinline__ float h2hi(uint32_t u) {
  union { uint32_t u; __half2 h; } v; v.u = u;
  return __half2float(v.h.y);
}
// tanh(x) = 1 - 2/(e^{2x}+1); upper clamp only (e^{2x} underflows cleanly to 0)
static __device__ __forceinline__ float tanh_fast(float x) {
  const float xc = fminf(x, 9.0f);
  const float e = __builtin_amdgcn_exp2f(xc * 2.8853900817779268f);  // 2*log2(e)
  return __builtin_fmaf(-2.0f, __builtin_amdgcn_rcpf(e + 1.0f), 1.0f);
}

// byte address of bf16 element (m=batch row, n=k/hidden col) in the swizzled
// 64x512 LDS tile. Row stride 1024 B; 16B chunks XOR-swizzled by (m&15).
static __device__ __forceinline__ int lds_ea(int m, int n) {
  return m * 1024 + ((((n >> 3) ^ (m & 15)) << 4)) + ((n & 7) << 1);
}

// Swapped-operand GEMM: D[hidden][batch] += W * h^T.
// A = weight frags (packed global stream, A-layout), B = h rows from LDS.
// acc[i][j]: i = hidden 16-tile (wave base 64w), j = batch 16-tile.
// Ap must be pre-offset: Ap + (4w*NKSEG)*512 + lane*8.
template <int NKSEG>
static __device__ __forceinline__ void mm_sw(const __bf16* __restrict__ Ap,
                                             const char* lds, int B1,
                                             f32x4 acc[4][4]) {
#pragma unroll
  for (int ks = 0; ks < NKSEG; ++ks) {
    bf16x8 wf[4];
#pragma unroll
    for (int i = 0; i < 4; ++i)
      wf[i] = *(const bf16x8*)(Ap + (size_t)(i * NKSEG + ks) * 512);
    const int ba = (B1 ^ ((ks & 3) << 6)) + ((ks >> 2) << 8);
#pragma unroll
    for (int j = 0; j < 4; ++j) {
      const bf16x8 hf = *(const bf16x8*)(lds + ba + j * 16384);
#pragma unroll
      for (int i = 0; i < 4; ++i)
        acc[i][j] =
            __builtin_amdgcn_mfma_f32_16x16x32_bf16(wf[i], hf, acc[i][j], 0, 0, 0);
    }
  }
}

__global__ __launch_bounds__(TPB, 2) void liq_main(
    const float* __restrict__ x, const float* __restrict__ bx,
    const float* __restrict__ bvec, const float* __restrict__ tau,
    const float* __restrict__ bfh, const __bf16* __restrict__ Wx_p,
    const __bf16* __restrict__ U_p, const __bf16* __restrict__ W_p,
    const __bf16* __restrict__ Wf_p, float* __restrict__ out) {
  __shared__ __align__(16) char abuf[BT * 1024];  // 64 KB operand buffer
  __shared__ __align__(8) uint2 drv[16 * TPB];    // 64 KB drive (bf16 pairs)
  __shared__ __align__(8) uint2 itl[4 * TPB];     // 16 KB 1/tau (bf16 pairs)
  const int tid = threadIdx.x;
  const int w = tid >> 6;  // 8 waves; wave owns hidden [64w, 64w+64)
  const int lane = tid & 63;
  const int l15 = lane & 15;
  const int q = lane >> 4;
  const int row0 = blockIdx.x * BT;

  // B-frag read base: addr(ks,j) = (B1 ^ ((ks&3)<<6)) + (ks>>2)*256 + j*16384
  const int B1 =
      l15 * 1024 + ((q ^ (l15 & 3)) << 4) + (((l15 >> 2) & 3) << 6);
  // stage/readback base: addr(i,j) = (A0 ^ (i<<5)) + j*16384
  // (element: batch row 16j+l15, hidden cols 64w+16i+4q .. +3, b64)
  const int chunk0 = (((q >> 1) ^ (l15 & 1))) | (((l15 >> 1) & 3) << 1) |
                     ((8 * w) ^ (l15 & 8));
  const int A0 = l15 * 1024 + ((q & 1) << 3) + (chunk0 << 4);

  // ---- stage x tile (64 x 256 fp32 -> bf16) ----
  {
    const float4* x4 = (const float4*)(x + (size_t)row0 * IN_DIM);
#pragma unroll
    for (int it = 0; it < (BT * IN_DIM / 4) / TPB; ++it) {  // 8
      const int id = tid + it * TPB;
      const float4 v = x4[id];
      const int m = id >> 6;
      const int c = (id & 63) << 2;
      uint2 pk;
      pk.x = f2bf(v.x) | (f2bf(v.y) << 16);
      pk.y = f2bf(v.z) | (f2bf(v.w) << 16);
      *(uint2*)(abuf + lds_ea(m, c)) = pk;  // (c&7) in {0,4} -> 8B aligned
    }
  }

  // 1/tau -> LDS (bf16 pairs; lane's hidden cols are 64w+16i+4q+r, r=0..3)
#pragma unroll
  for (int i = 0; i < 4; ++i) {
    const float4 tv = *(const float4*)(tau + 64 * w + 16 * i + 4 * q);
    uint2 pk;
    pk.x = f2bf(1.0f / tv.x) | (f2bf(1.0f / tv.y) << 16);
    pk.y = f2bf(1.0f / tv.z) | (f2bf(1.0f / tv.w) << 16);
    itl[i * TPB + tid] = pk;  // own-write / own-read
  }
  __syncthreads();

  // ---- u = x @ Wx^T + bx (A = Wx frags, B = x) ----
  f32x4 acc[4][4];
#pragma unroll
  for (int i = 0; i < 4; ++i) {
    const float4 b4 = *(const float4*)(bx + 64 * w + 16 * i + 4 * q);
#pragma unroll
    for (int j = 0; j < 4; ++j) acc[i][j] = (f32x4){b4.x, b4.y, b4.z, b4.w};
  }
  mm_sw<IN_DIM / 32>(Wx_p + (size_t)w * 16384 + lane * 8, abuf, B1, acc);

  uint32_t h16[32];  // h state, fp16 pairs (RNE) — keeps arch VGPRs <= 128
#pragma unroll
  for (int i = 0; i < 4; ++i)
#pragma unroll
    for (int j = 0; j < 4; ++j) {
      const int ti = i * 4 + j;
      h16[ti * 2] = pkh(acc[i][j][0], acc[i][j][1]);
      h16[ti * 2 + 1] = pkh(acc[i][j][2], acc[i][j][3]);
    }

  __syncthreads();  // all waves done reading x before overwrite
#pragma unroll
  for (int i = 0; i < 4; ++i)
#pragma unroll
    for (int j = 0; j < 4; ++j) {
      uint2 pk;
      pk.x = f2bf(acc[i][j][0]) | (f2bf(acc[i][j][1]) << 16);
      pk.y = f2bf(acc[i][j][2]) | (f2bf(acc[i][j][3]) << 16);
      *(uint2*)(abuf + ((A0 ^ (i << 5)) + j * 16384)) = pk;
    }
  __syncthreads();

  // ---- drive = u @ U^T + b ----
#pragma unroll
  for (int i = 0; i < 4; ++i) {
    const float4 b4 = *(const float4*)(bvec + 64 * w + 16 * i + 4 * q);
#pragma unroll
    for (int j = 0; j < 4; ++j) acc[i][j] = (f32x4){b4.x, b4.y, b4.z, b4.w};
  }
  mm_sw<HID / 32>(U_p + (size_t)w * 32768 + lane * 8, abuf, B1, acc);
#pragma unroll
  for (int i = 0; i < 4; ++i)
#pragma unroll
    for (int j = 0; j < 4; ++j) {
      uint2 pk;
      pk.x = f2bf(acc[i][j][0]) | (f2bf(acc[i][j][1]) << 16);
      pk.y = f2bf(acc[i][j][2]) | (f2bf(acc[i][j][3]) << 16);
      drv[(i * 4 + j) * TPB + tid] = pk;  // own-write / own-read
    }

  const float dt = 1.0f / NSTEPS;
  const float hdt = 0.5f * dt;
  const float dt6 = dt / 6.0f;
  uint32_t Sp[32];  // RK4 sum, bf16 pairs

  for (int st = 0; st < NSTEPS; ++st) {
    for (int e = 0; e < 4; ++e) {  // k1..k4 (rolled: I-cache)
      // acc <- drive
#pragma unroll
      for (int i = 0; i < 4; ++i)
#pragma unroll
        for (int j = 0; j < 4; ++j) {
          const uint2 d = drv[(i * 4 + j) * TPB + tid];
          acc[i][j] = (f32x4){bflo(d.x), bfhi(d.x), bflo(d.y), bfhi(d.y)};
        }
      mm_sw<HID / 32>(W_p + (size_t)w * 32768 + lane * 8, abuf, B1, acc);

      const float wk = (e == 1 || e == 2) ? 2.0f : 1.0f;
      const float cn = (e < 2) ? hdt : ((e == 2) ? dt : dt6);
#pragma unroll
      for (int i = 0; i < 4; ++i)
#pragma unroll
        for (int j = 0; j < 4; ++j) {
          const int ti = i * 4 + j;
          const int sa = (A0 ^ (i << 5)) + j * 16384;
          const float hc[4] = {h2lo(h16[ti * 2]), h2hi(h16[ti * 2]),
                               h2lo(h16[ti * 2 + 1]), h2hi(h16[ti * 2 + 1])};
          float hin[4];
          if (e == 0) {
#pragma unroll
            for (int r = 0; r < 4; ++r) hin[r] = hc[r];
          } else {  // staged h_tmp (bf16) from LDS
            const uint2 hb = *(const uint2*)(abuf + sa);
            hin[0] = bflo(hb.x); hin[1] = bfhi(hb.x);
            hin[2] = bflo(hb.y); hin[3] = bfhi(hb.y);
          }
          const uint2 it2 = itl[i * TPB + tid];
          const float itv[4] = {bflo(it2.x), bfhi(it2.x), bflo(it2.y),
                                bfhi(it2.y)};
          float kk[4];
#pragma unroll
          for (int r = 0; r < 4; ++r)
            kk[r] = (tanh_fast(acc[i][j][r]) - hin[r]) * itv[r];
          float sv[4];
          if (e == 0) {
            sv[0] = kk[0]; sv[1] = kk[1]; sv[2] = kk[2]; sv[3] = kk[3];
          } else {
            const uint32_t s01 = Sp[ti * 2], s23 = Sp[ti * 2 + 1];
            sv[0] = bflo(s01) + wk * kk[0];
            sv[1] = bfhi(s01) + wk * kk[1];
            sv[2] = bflo(s23) + wk * kk[2];
            sv[3] = bfhi(s23) + wk * kk[3];
          }
          if (e < 3) {
            Sp[ti * 2] = f2bf(sv[0]) | (f2bf(sv[1]) << 16);
            Sp[ti * 2 + 1] = f2bf(sv[2]) | (f2bf(sv[3]) << 16);
          }
          float nxt[4];
#pragma unroll
          for (int r = 0; r < 4; ++r) {
            nxt[r] = hc[r] + cn * ((e == 3) ? sv[r] : kk[r]);
            acc[i][j][r] = nxt[r];  // staging for LDS write
          }
          if (e == 3) {  // RK4 state update (fp16 RNE)
            h16[ti * 2] = pkh(nxt[0], nxt[1]);
            h16[ti * 2 + 1] = pkh(nxt[2], nxt[3]);
          }
        }
      __syncthreads();  // all LDS reads (B frags + h_in) complete
#pragma unroll
      for (int i = 0; i < 4; ++i)
#pragma unroll
        for (int j = 0; j < 4; ++j) {
          uint2 pk;
          pk.x = f2bf(acc[i][j][0]) | (f2bf(acc[i][j][1]) << 16);
          pk.y = f2bf(acc[i][j][2]) | (f2bf(acc[i][j][3]) << 16);
          *(uint2*)(abuf + ((A0 ^ (i << 5)) + j * 16384)) = pk;
        }
      __syncthreads();  // next operand visible to all waves
    }
  }

  // ---- head: out = h_T @ Wf^T + bf (A = Wf frags; wave w -> out cols 16w..) --
  {
    const float4 b4 = *(const float4*)(bfh + 16 * w + 4 * q);
    f32x4 a2[4];
#pragma unroll
    for (int j = 0; j < 4; ++j) a2[j] = (f32x4){b4.x, b4.y, b4.z, b4.w};
#pragma unroll
    for (int ks = 0; ks < HID / 32; ++ks) {
      const bf16x8 wf =
          *(const bf16x8*)(Wf_p + (size_t)(w * 16 + ks) * 512 + lane * 8);
      const int ba = (B1 ^ ((ks & 3) << 6)) + ((ks >> 2) << 8);
#pragma unroll
      for (int j = 0; j < 4; ++j) {
        const bf16x8 hf = *(const bf16x8*)(abuf + ba + j * 16384);
        a2[j] = __builtin_amdgcn_mfma_f32_16x16x32_bf16(wf, hf, a2[j], 0, 0, 0);
      }
    }
#pragma unroll
    for (int j = 0; j < 4; ++j) {
      float4 o;
      o.x = a2[j][0]; o.y = a2[j][1]; o.z = a2[j][2]; o.w = a2[j][3];
      *(float4*)(out + (size_t)(row0 + 16 * j + l15) * OUT_DIM + 16 * w +
                 4 * q) = o;
    }
  }
}

// Pack row-major fp32 weight [N][K] into bf16 frag stream (16-row tiles):
// dst[((nt*KSEG + ks)*64 + lane)*8 + j] = W[nt*16 + (lane&15)][ks*32 + (lane>>4)*8 + j]
__global__ void pack_bfrag(const float* __restrict__ src, __bf16* __restrict__ dst,
                           int K, int kslog, int total) {
  const int i = blockIdx.x * blockDim.x + threadIdx.x;
  if (i >= total) return;
  const int j = i & 7;
  const int lane = (i >> 3) & 63;
  const int rem = i >> 9;
  const int ks = rem & ((1 << kslog) - 1);
  const int nt = rem >> kslog;
  const int n = (nt << 4) + (lane & 15);
  const int k = (ks << 5) + ((lane >> 4) << 3) + j;
  dst[i] = (__bf16)src[n * K + k];
}

extern "C" void kernel_launch(void* const* d_in, const int* in_sizes, int n_in,
                              void* d_out, int out_size, void* d_ws, size_t ws_size,
                              hipStream_t stream) {
  const float* x = (const float*)d_in[0];
  const float* Wx = (const float*)d_in[1];
  const float* bx = (const float*)d_in[2];
  const float* W = (const float*)d_in[3];
  const float* U = (const float*)d_in[4];
  const float* b = (const float*)d_in[5];
  const float* tau = (const float*)d_in[6];
  const float* Wf = (const float*)d_in[7];
  const float* bf_ = (const float*)d_in[8];
  float* out = (float*)d_out;

  char* ws = (char*)d_ws;  // 1.375 MB used
  __bf16* W_p = (__bf16*)(ws + 0);
  __bf16* U_p = (__bf16*)(ws + (512 * 1024));
  __bf16* Wx_p = (__bf16*)(ws + (1024 * 1024));
  __bf16* Wf_p = (__bf16*)(ws + (1280 * 1024));

  pack_bfrag<<<(HID * HID) / 256, 256, 0, stream>>>(W, W_p, HID, 4, HID * HID);
  pack_bfrag<<<(HID * HID) / 256, 256, 0, stream>>>(U, U_p, HID, 4, HID * HID);
  pack_bfrag<<<(HID * IN_DIM) / 256, 256, 0, stream>>>(Wx, Wx_p, IN_DIM, 3,
                                                       HID * IN_DIM);
  pack_bfrag<<<(OUT_DIM * HID) / 256, 256, 0, stream>>>(Wf, Wf_p, HID, 4,
                                                        OUT_DIM * HID);

  liq_main<<<32768 / BT, TPB, 0, stream>>>(x, bx, b, tau, bf_, Wx_p, U_p, W_p,
                                           Wf_p, out);
}

// Round 8
// 3522.879 us; speedup vs baseline: 15.2029x; 15.2029x over previous
//
#include <hip/hip_runtime.h>
#include <stdint.h>

#define IN_DIM 256
#define HID 512
#define OUT_DIM 128
#define BT 64
#define NSTEPS 40
#define TPB 512

typedef float f32x4 __attribute__((ext_vector_type(4)));
typedef __bf16 bf16x8 __attribute__((ext_vector_type(8)));

static __device__ __forceinline__ uint32_t f2bf(float f) {
  union { float f; uint32_t u; } v; v.f = f;
  uint32_t r = v.u + 0x7FFFu + ((v.u >> 16) & 1u);  // RNE
  return r >> 16;
}
static __device__ __forceinline__ float bflo(uint32_t u) {
  union { uint32_t u; float f; } v; v.u = u << 16; return v.f;
}
static __device__ __forceinline__ float bfhi(uint32_t u) {
  union { uint32_t u; float f; } v; v.u = u & 0xFFFF0000u; return v.f;
}
// fp16 pair pack/unpack — INTEGER-SCALAR ONLY (R7: __half2 struct unions
// defeat SROA -> whole state array lands in scratch, 45 GB of traffic).
// _Float16 casts emit single v_cvt_f16_f32 / v_cvt_f32_f16 (RNE).
static __device__ __forceinline__ uint32_t pkh(float a, float b) {
  const uint16_t lo = __builtin_bit_cast(uint16_t, (_Float16)a);
  const uint16_t hi = __builtin_bit_cast(uint16_t, (_Float16)b);
  return (uint32_t)lo | ((uint32_t)hi << 16);
}
static __device__ __forceinline__ float h2lo(uint32_t u) {
  return (float)__builtin_bit_cast(_Float16, (uint16_t)(u & 0xFFFFu));
}
static __device__ __forceinline__ float h2hi(uint32_t u) {
  return (float)__builtin_bit_cast(_Float16, (uint16_t)(u >> 16));
}
// tanh(x) = 1 - 2/(e^{2x}+1); upper clamp only (e^{2x} underflows cleanly to 0)
static __device__ __forceinline__ float tanh_fast(float x) {
  const float xc = fminf(x, 9.0f);
  const float e = __builtin_amdgcn_exp2f(xc * 2.8853900817779268f);  // 2*log2(e)
  return __builtin_fmaf(-2.0f, __builtin_amdgcn_rcpf(e + 1.0f), 1.0f);
}

// byte address of bf16 element (m=batch row, n=k/hidden col) in the swizzled
// 64x512 LDS tile. Row stride 1024 B; 16B chunks XOR-swizzled by (m&15).
static __device__ __forceinline__ int lds_ea(int m, int n) {
  return m * 1024 + ((((n >> 3) ^ (m & 15)) << 4)) + ((n & 7) << 1);
}

// Swapped-operand GEMM: D[hidden][batch] += W * h^T.
// A = weight frags (packed global stream, A-layout), B = h rows from LDS.
// acc[i][j]: i = hidden 16-tile (wave base 64w), j = batch 16-tile.
// Ap must be pre-offset: Ap + (4w*NKSEG)*512 + lane*8.
// i-pair structure + unroll 2: caps live frag regs at ~24 (R5's full 16x
// unroll let the scheduler hoist several iterations of wf loads -> spill).
// hf re-read across the two i-pairs: LDS traffic 2x (1 MB/CU/eval), still
// on par with the 9.9k-cyc MFMA floor.
template <int NKSEG>
static __device__ __forceinline__ void mm_sw(const __bf16* __restrict__ Ap,
                                             const char* lds, int B1,
                                             f32x4 acc[4][4]) {
#pragma unroll 2
  for (int ks = 0; ks < NKSEG; ++ks) {
    const int ba = (B1 ^ ((ks & 3) << 6)) + ((ks >> 2) << 8);
#pragma unroll
    for (int ih = 0; ih < 2; ++ih) {
      const bf16x8 wf0 =
          *(const bf16x8*)(Ap + (size_t)((2 * ih) * NKSEG + ks) * 512);
      const bf16x8 wf1 =
          *(const bf16x8*)(Ap + (size_t)((2 * ih + 1) * NKSEG + ks) * 512);
#pragma unroll
      for (int j = 0; j < 4; ++j) {
        const bf16x8 hf = *(const bf16x8*)(lds + ba + j * 16384);
        acc[2 * ih][j] = __builtin_amdgcn_mfma_f32_16x16x32_bf16(
            wf0, hf, acc[2 * ih][j], 0, 0, 0);
        acc[2 * ih + 1][j] = __builtin_amdgcn_mfma_f32_16x16x32_bf16(
            wf1, hf, acc[2 * ih + 1][j], 0, 0, 0);
      }
    }
  }
}

__global__ __launch_bounds__(TPB, 2) void liq_main(
    const float* __restrict__ x, const float* __restrict__ bx,
    const float* __restrict__ bvec, const float* __restrict__ tau,
    const float* __restrict__ bfh, const __bf16* __restrict__ Wx_p,
    const __bf16* __restrict__ U_p, const __bf16* __restrict__ W_p,
    const __bf16* __restrict__ Wf_p, float* __restrict__ out) {
  __shared__ __align__(16) char abuf[BT * 1024];  // 64 KB operand buffer
  __shared__ __align__(8) uint2 drv[16 * TPB];    // 64 KB drive (bf16 pairs)
  const int tid = threadIdx.x;
  const int w = tid >> 6;  // 8 waves; wave owns hidden [64w, 64w+64)
  const int lane = tid & 63;
  const int l15 = lane & 15;
  const int q = lane >> 4;
  const int row0 = blockIdx.x * BT;

  // B-frag read base: addr(ks,j) = (B1 ^ ((ks&3)<<6)) + (ks>>2)*256 + j*16384
  const int B1 =
      l15 * 1024 + ((q ^ (l15 & 3)) << 4) + (((l15 >> 2) & 3) << 6);
  // stage/readback base: addr(i,j) = (A0 ^ (i<<5)) + j*16384
  // (element: batch row 16j+l15, hidden cols 64w+16i+4q .. +3, b64)
  const int chunk0 = (((q >> 1) ^ (l15 & 1))) | (((l15 >> 1) & 3) << 1) |
                     ((8 * w) ^ (l15 & 8));
  const int A0 = l15 * 1024 + ((q & 1) << 3) + (chunk0 << 4);

  // ---- stage x tile (64 x 256 fp32 -> bf16) ----
  {
    const float4* x4 = (const float4*)(x + (size_t)row0 * IN_DIM);
#pragma unroll
    for (int it = 0; it < (BT * IN_DIM / 4) / TPB; ++it) {  // 8
      const int id = tid + it * TPB;
      const float4 v = x4[id];
      const int m = id >> 6;
      const int c = (id & 63) << 2;
      uint2 pk;
      pk.x = f2bf(v.x) | (f2bf(v.y) << 16);
      pk.y = f2bf(v.z) | (f2bf(v.w) << 16);
      *(uint2*)(abuf + lds_ea(m, c)) = pk;  // (c&7) in {0,4} -> 8B aligned
    }
  }

  // itau (bf16-packed regs): lane's hidden cols are 64w+16i+4q+r
  uint32_t itp[8];
#pragma unroll
  for (int i = 0; i < 4; ++i) {
    const float4 tv = *(const float4*)(tau + 64 * w + 16 * i + 4 * q);
    itp[i * 2 + 0] = f2bf(1.0f / tv.x) | (f2bf(1.0f / tv.y) << 16);
    itp[i * 2 + 1] = f2bf(1.0f / tv.z) | (f2bf(1.0f / tv.w) << 16);
  }
  __syncthreads();

  // ---- u = x @ Wx^T + bx (A = Wx frags, B = x) ----
  f32x4 acc[4][4];
#pragma unroll
  for (int i = 0; i < 4; ++i) {
    const float4 b4 = *(const float4*)(bx + 64 * w + 16 * i + 4 * q);
#pragma unroll
    for (int j = 0; j < 4; ++j) acc[i][j] = (f32x4){b4.x, b4.y, b4.z, b4.w};
  }
  mm_sw<IN_DIM / 32>(Wx_p + (size_t)w * 16384 + lane * 8, abuf, B1, acc);

  uint32_t h16[32];  // h state, fp16 pairs (integer-packed, SROA-safe)
#pragma unroll
  for (int i = 0; i < 4; ++i)
#pragma unroll
    for (int j = 0; j < 4; ++j) {
      const int ti = i * 4 + j;
      h16[ti * 2] = pkh(acc[i][j][0], acc[i][j][1]);
      h16[ti * 2 + 1] = pkh(acc[i][j][2], acc[i][j][3]);
    }

  __syncthreads();  // all waves done reading x before overwrite
#pragma unroll
  for (int i = 0; i < 4; ++i)
#pragma unroll
    for (int j = 0; j < 4; ++j) {
      uint2 pk;
      pk.x = f2bf(acc[i][j][0]) | (f2bf(acc[i][j][1]) << 16);
      pk.y = f2bf(acc[i][j][2]) | (f2bf(acc[i][j][3]) << 16);
      *(uint2*)(abuf + ((A0 ^ (i << 5)) + j * 16384)) = pk;
    }
  __syncthreads();

  // ---- drive = u @ U^T + b ----
#pragma unroll
  for (int i = 0; i < 4; ++i) {
    const float4 b4 = *(const float4*)(bvec + 64 * w + 16 * i + 4 * q);
#pragma unroll
    for (int j = 0; j < 4; ++j) acc[i][j] = (f32x4){b4.x, b4.y, b4.z, b4.w};
  }
  mm_sw<HID / 32>(U_p + (size_t)w * 32768 + lane * 8, abuf, B1, acc);
#pragma unroll
  for (int i = 0; i < 4; ++i)
#pragma unroll
    for (int j = 0; j < 4; ++j) {
      uint2 pk;
      pk.x = f2bf(acc[i][j][0]) | (f2bf(acc[i][j][1]) << 16);
      pk.y = f2bf(acc[i][j][2]) | (f2bf(acc[i][j][3]) << 16);
      drv[(i * 4 + j) * TPB + tid] = pk;  // own-write / own-read
    }

  const float dt = 1.0f / NSTEPS;
  const float hdt = 0.5f * dt;
  const float dt6 = dt / 6.0f;
  uint32_t Sp[32];  // RK4 sum, bf16 pairs (integer-packed)

  for (int st = 0; st < NSTEPS; ++st) {
    for (int e = 0; e < 4; ++e) {  // k1..k4 (rolled: I-cache)
      // acc <- drive
#pragma unroll
      for (int i = 0; i < 4; ++i)
#pragma unroll
        for (int j = 0; j < 4; ++j) {
          const uint2 d = drv[(i * 4 + j) * TPB + tid];
          acc[i][j] = (f32x4){bflo(d.x), bfhi(d.x), bflo(d.y), bfhi(d.y)};
        }
      mm_sw<HID / 32>(W_p + (size_t)w * 32768 + lane * 8, abuf, B1, acc);

      const float wk = (e == 1 || e == 2) ? 2.0f : 1.0f;
      const float cn = (e < 2) ? hdt : ((e == 2) ? dt : dt6);
#pragma unroll
      for (int i = 0; i < 4; ++i)
#pragma unroll
        for (int j = 0; j < 4; ++j) {
          const int ti = i * 4 + j;
          const int sa = (A0 ^ (i << 5)) + j * 16384;
          const float hc0 = h2lo(h16[ti * 2]), hc1 = h2hi(h16[ti * 2]);
          const float hc2 = h2lo(h16[ti * 2 + 1]), hc3 = h2hi(h16[ti * 2 + 1]);
          float hin[4];
          if (e == 0) {
            hin[0] = hc0; hin[1] = hc1; hin[2] = hc2; hin[3] = hc3;
          } else {  // staged h_tmp (bf16) from LDS
            const uint2 hb = *(const uint2*)(abuf + sa);
            hin[0] = bflo(hb.x); hin[1] = bfhi(hb.x);
            hin[2] = bflo(hb.y); hin[3] = bfhi(hb.y);
          }
          float kk[4];
          kk[0] = (tanh_fast(acc[i][j][0]) - hin[0]) * bflo(itp[i * 2]);
          kk[1] = (tanh_fast(acc[i][j][1]) - hin[1]) * bfhi(itp[i * 2]);
          kk[2] = (tanh_fast(acc[i][j][2]) - hin[2]) * bflo(itp[i * 2 + 1]);
          kk[3] = (tanh_fast(acc[i][j][3]) - hin[3]) * bfhi(itp[i * 2 + 1]);
          float sv[4];
          if (e == 0) {
            sv[0] = kk[0]; sv[1] = kk[1]; sv[2] = kk[2]; sv[3] = kk[3];
          } else {
            const uint32_t s01 = Sp[ti * 2], s23 = Sp[ti * 2 + 1];
            sv[0] = bflo(s01) + wk * kk[0];
            sv[1] = bfhi(s01) + wk * kk[1];
            sv[2] = bflo(s23) + wk * kk[2];
            sv[3] = bfhi(s23) + wk * kk[3];
          }
          if (e < 3) {
            Sp[ti * 2] = f2bf(sv[0]) | (f2bf(sv[1]) << 16);
            Sp[ti * 2 + 1] = f2bf(sv[2]) | (f2bf(sv[3]) << 16);
          }
          const float n0 = hc0 + cn * ((e == 3) ? sv[0] : kk[0]);
          const float n1 = hc1 + cn * ((e == 3) ? sv[1] : kk[1]);
          const float n2 = hc2 + cn * ((e == 3) ? sv[2] : kk[2]);
          const float n3 = hc3 + cn * ((e == 3) ? sv[3] : kk[3]);
          if (e == 3) {  // RK4 state update (fp16 RNE, integer-packed)
            h16[ti * 2] = pkh(n0, n1);
            h16[ti * 2 + 1] = pkh(n2, n3);
          }
          acc[i][j][0] = n0; acc[i][j][1] = n1;  // staging for LDS write
          acc[i][j][2] = n2; acc[i][j][3] = n3;
        }
      __syncthreads();  // all LDS reads (B frags + h_in) complete
#pragma unroll
      for (int i = 0; i < 4; ++i)
#pragma unroll
        for (int j = 0; j < 4; ++j) {
          uint2 pk;
          pk.x = f2bf(acc[i][j][0]) | (f2bf(acc[i][j][1]) << 16);
          pk.y = f2bf(acc[i][j][2]) | (f2bf(acc[i][j][3]) << 16);
          *(uint2*)(abuf + ((A0 ^ (i << 5)) + j * 16384)) = pk;
        }
      __syncthreads();  // next operand visible to all waves
    }
  }

  // ---- head: out = h_T @ Wf^T + bf (A = Wf frags; wave w -> out cols 16w..) --
  {
    const float4 b4 = *(const float4*)(bfh + 16 * w + 4 * q);
    f32x4 a2[4];
#pragma unroll
    for (int j = 0; j < 4; ++j) a2[j] = (f32x4){b4.x, b4.y, b4.z, b4.w};
#pragma unroll 2
    for (int ks = 0; ks < HID / 32; ++ks) {
      const bf16x8 wf =
          *(const bf16x8*)(Wf_p + (size_t)(w * 16 + ks) * 512 + lane * 8);
      const int ba = (B1 ^ ((ks & 3) << 6)) + ((ks >> 2) << 8);
#pragma unroll
      for (int j = 0; j < 4; ++j) {
        const bf16x8 hf = *(const bf16x8*)(abuf + ba + j * 16384);
        a2[j] = __builtin_amdgcn_mfma_f32_16x16x32_bf16(wf, hf, a2[j], 0, 0, 0);
      }
    }
#pragma unroll
    for (int j = 0; j < 4; ++j) {
      float4 o;
      o.x = a2[j][0]; o.y = a2[j][1]; o.z = a2[j][2]; o.w = a2[j][3];
      *(float4*)(out + (size_t)(row0 + 16 * j + l15) * OUT_DIM + 16 * w +
                 4 * q) = o;
    }
  }
}

// Pack row-major fp32 weight [N][K] into bf16 frag stream (16-row tiles):
// dst[((nt*KSEG + ks)*64 + lane)*8 + j] = W[nt*16 + (lane&15)][ks*32 + (lane>>4)*8 + j]
__global__ void pack_bfrag(const float* __restrict__ src, __bf16* __restrict__ dst,
                           int K, int kslog, int total) {
  const int i = blockIdx.x * blockDim.x + threadIdx.x;
  if (i >= total) return;
  const int j = i & 7;
  const int lane = (i >> 3) & 63;
  const int rem = i >> 9;
  const int ks = rem & ((1 << kslog) - 1);
  const int nt = rem >> kslog;
  const int n = (nt << 4) + (lane & 15);
  const int k = (ks << 5) + ((lane >> 4) << 3) + j;
  dst[i] = (__bf16)src[n * K + k];
}

extern "C" void kernel_launch(void* const* d_in, const int* in_sizes, int n_in,
                              void* d_out, int out_size, void* d_ws, size_t ws_size,
                              hipStream_t stream) {
  const float* x = (const float*)d_in[0];
  const float* Wx = (const float*)d_in[1];
  const float* bx = (const float*)d_in[2];
  const float* W = (const float*)d_in[3];
  const float* U = (const float*)d_in[4];
  const float* b = (const float*)d_in[5];
  const float* tau = (const float*)d_in[6];
  const float* Wf = (const float*)d_in[7];
  const float* bf_ = (const float*)d_in[8];
  float* out = (float*)d_out;

  char* ws = (char*)d_ws;  // 1.375 MB used
  __bf16* W_p = (__bf16*)(ws + 0);
  __bf16* U_p = (__bf16*)(ws + (512 * 1024));
  __bf16* Wx_p = (__bf16*)(ws + (1024 * 1024));
  __bf16* Wf_p = (__bf16*)(ws + (1280 * 1024));

  pack_bfrag<<<(HID * HID) / 256, 256, 0, stream>>>(W, W_p, HID, 4, HID * HID);
  pack_bfrag<<<(HID * HID) / 256, 256, 0, stream>>>(U, U_p, HID, 4, HID * HID);
  pack_bfrag<<<(HID * IN_DIM) / 256, 256, 0, stream>>>(Wx, Wx_p, IN_DIM, 3,
                                                       HID * IN_DIM);
  pack_bfrag<<<(OUT_DIM * HID) / 256, 256, 0, stream>>>(Wf, Wf_p, HID, 4,
                                                        OUT_DIM * HID);

  liq_main<<<32768 / BT, TPB, 0, stream>>>(x, bx, b, tau, bf_, Wx_p, U_p, W_p,
                                           Wf_p, out);
}